// Round 12
// baseline (207.335 us; speedup 1.0000x reference)
//
#include <hip/hip_runtime.h>
#include <math.h>

#define NB 4
#define NM 32
#define CTOT 282
#define EPSV 1e-3f

__constant__ int g_cL[5]   = {192,48,24,12,6};
__constant__ int g_hL[5]   = {2,4,8,16,32};
__constant__ int g_coff[5] = {0,192,240,264,276};
__constant__ int g_zo[5]   = {0,768,1536,3072,6144};
__constant__ int g_po[4]   = {0,4,20,84};

// 48 level-homogeneous d-tiles
__constant__ int t_lo[48] = {0,0,0,0,0,0,0,0,0,0,0,0,0,0,0,0,
                             0,0,0,0,0,0,0,0,0,0,0,0,0,0,0,0,
                             1,1,1,1,1,1,1,1, 2,2,2,2, 3,3, 4,4};
__constant__ int t_d0[48] = {0,6,12,18,24,30,36,42,48,54,60,66,72,78,84,90,
                             96,102,108,114,120,126,132,138,144,150,156,162,168,174,180,186,
                             192,198,204,210,216,222,228,234, 240,246,252,258, 264,270, 276,279};
__constant__ int t_nd[48] = {6,6,6,6,6,6,6,6,6,6,6,6,6,6,6,6,
                             6,6,6,6,6,6,6,6,6,6,6,6,6,6,6,6,
                             6,6,6,6,6,6,6,6, 6,6,6,6, 6,6, 3,3};

// dft sub-block tables (30 per (which,b)): level + channel offset
__constant__ int dft_l[30]  = {0,0,0, 1,1,1, 2,2,2,2,2,2,
                               3,3,3,3,3,3,3,3,3,3,3,3, 4,4,4,4,4,4};
__constant__ int dft_c0[30] = {0,64,128, 0,16,32, 0,4,8,12,16,20,
                               0,1,2,3,4,5,6,7,8,9,10,11, 0,1,2,3,4,5};
__constant__ int dft_nc2[30] = {64,64,64, 16,16,16, 4,4,4,4,4,4,
                                1,1,1,1,1,1,1,1,1,1,1,1, 1,1,1,1,1,1};

// LAT tile pairs (i<=j), 15 per m
__constant__ int p_i[15] = {0,0,0,0,0,1,1,1,1,2,2,2,3,3,4};
__constant__ int p_j[15] = {0,1,2,3,4,1,2,3,4,2,3,4,3,4,4};

// workspace layout (float offsets)
#define N_LA     (NM*CTOT*CTOT)
#define OFF_LAT  0
#define OFF_ZRE  (OFF_LAT + N_LA)
#define OFF_ZIM  (OFF_ZRE + NB*12288)
#define OFF_WRE  (OFF_ZIM + NB*12288)
#define OFF_WIM  (OFF_WRE + NB*12288)
#define OFF_LAM  (OFF_WIM + NB*12288)
#define OFF_LAMF (OFF_LAM + NM*1024)
#define OFF_ZTR  (OFF_LAMF + NM*340)
#define OFF_ZTI  (OFF_ZTR + NB*6144)
#define OFF_UR   (OFF_ZTI + NB*6144)
#define OFF_UI   (OFF_UR + NB*NM*2720)
#define OFF_VRE  (OFF_UI + NB*NM*2720)
#define OFF_VIM  (OFF_VRE + NB*NM*12288)
#define OFF_SZZ  (OFF_VIM + NB*NM*12288)
#define OFF_SZW  (OFF_SZZ + NB*NM*NM)
#define OFF_SWW  (OFF_SZW + NB*NM)

// k_pre bid ranges: UGEN first (longest-running, overlaps LAT's HBM latency)
#define PRE_UGEN  (NB*6*NM)             /* 768 */
#define PRE_LAT   (PRE_UGEN + NM*15)    /* +480 -> 1248 */
#define PRE_LAMF  (PRE_LAT + NM)        /* +32  -> 1280 */
#define PRE_DFT   (PRE_LAMF + 2*NB*30)  /* +240 -> 1520 */
#define PRE_SWW   (PRE_DFT + NB)        /* +4   -> 1524 */
#define PRE_TOT   (PRE_SWW + 17)        /* +17  -> 1541 */

// merged: UGEN + paired LaT + lamA/lamfold + DFTs (z0-3 transposed) + S_ww + SZZ zero
__global__ void __launch_bounds__(256) k_pre(
    const float* z0,const float* z1,const float* z2,const float* z3,const float* z4,
    const float* w0,const float* w1,const float* w2,const float* w3,const float* w4,
    const float* __restrict__ L, const float* __restrict__ lam, float* __restrict__ ws){
  __shared__ float shm[8320];
  int bid = blockIdx.x, t = threadIdx.x;
  if (bid < PRE_UGEN){
    // one (b, c4, m) per block: redundant 32x32 z4 DFT + lam-fold -> U slice
    float* sIn = shm;          // 1024
    float* s1r = shm + 1024;   // 1056
    float* s1i = shm + 2080;   // 1056
    float* zr  = shm + 3136;   // 1024
    float* zi  = shm + 4160;   // 1024
    float* sLam= shm + 5184;   // 1024
    float* lc  = shm + 6208;   // 32
    float* lsn = shm + 6240;   // 32
    float* u3r = shm + 6272;   // 256
    float* u3i = shm + 6528;   // 256
    float* u2r = shm + 6784;   // 64
    float* u2i = shm + 6848;   // 64
    float* u1r = shm + 6912;   // 16
    float* u1i = shm + 6928;   // 16
    int b = bid/192; int r2 = bid%192; int c = r2/32; int m = r2%32;
    const float* src = z4 + (b*6 + c)*1024;
    const float* lm = lam + (m<<10);
    for (int i=t;i<1024;i+=256){ sIn[i]=src[i]; sLam[i]=lm[i]; }
    if (t<32){
      float ang = -6.2831853071795864f * (float)t / 32.0f;
      lc[t]=cosf(ang); lsn[t]=sinf(ang);
    }
    __syncthreads();
    for (int p=t;p<1024;p+=256){
      int y=p>>5, kx=p&31;
      float re=0.f, im=0.f;
      for (int x=0;x<32;x++){
        int id=(kx*x)&31;
        float v=sIn[(y<<5)+x];
        re += v*lc[id]; im += v*lsn[id];
      }
      s1r[y*33+kx]=re; s1i[y*33+kx]=im;
    }
    __syncthreads();
    for (int p=t;p<1024;p+=256){
      int ky=p>>5, kx=p&31;
      float re=0.f, im=0.f;
      for (int y=0;y<32;y++){
        int id=(ky*y)&31;
        float cc=lc[id], ss=lsn[id];
        float ar=s1r[y*33+kx], ai=s1i[y*33+kx];
        re += ar*cc - ai*ss;
        im += ar*ss + ai*cc;
      }
      zr[p]=re; zi[p]=im;
    }
    __syncthreads();
    size_t base = (size_t)(b*NM+m)*2720;
    float* UR = ws+OFF_UR+base; float* UI = ws+OFF_UI+base;
    {
      int sy=t>>4, sx=t&15;
      float ur=0.f, ui=0.f;
      #pragma unroll
      for (int jy=0;jy<2;jy++)
        #pragma unroll
        for (int jx=0;jx<2;jx++){
          int ky=sy+16*jy, kx=sx+16*jx;
          int k=(ky<<5)|kx;
          int nk=(((32-ky)&31)<<5)|((32-kx)&31);
          float la = sLam[k]-sLam[nk];
          ur += la*zr[k]; ui += la*zi[k];
        }
      u3r[t]=ur; u3i[t]=ui;
      UR[(84+t)*8+c]=ur; UI[(84+t)*8+c]=ui;
    }
    __syncthreads();
    if (t<64){ int ky=t>>3, kx=t&7;
      float r = u3r[(ky<<4)+kx]+u3r[((ky+8)<<4)+kx]+u3r[(ky<<4)+kx+8]+u3r[((ky+8)<<4)+kx+8];
      float ii= u3i[(ky<<4)+kx]+u3i[((ky+8)<<4)+kx]+u3i[(ky<<4)+kx+8]+u3i[((ky+8)<<4)+kx+8];
      u2r[t]=r; u2i[t]=ii; UR[(20+t)*8+c]=r; UI[(20+t)*8+c]=ii; }
    __syncthreads();
    if (t<16){ int ky=t>>2, kx=t&3;
      float r = u2r[(ky<<3)+kx]+u2r[((ky+4)<<3)+kx]+u2r[(ky<<3)+kx+4]+u2r[((ky+4)<<3)+kx+4];
      float ii= u2i[(ky<<3)+kx]+u2i[((ky+4)<<3)+kx]+u2i[(ky<<3)+kx+4]+u2i[((ky+4)<<3)+kx+4];
      u1r[t]=r; u1i[t]=ii; UR[(4+t)*8+c]=r; UI[(4+t)*8+c]=ii; }
    __syncthreads();
    if (t<4){ int ky=t>>1, kx=t&1;
      float r = u1r[(ky<<2)+kx]+u1r[((ky+2)<<2)+kx]+u1r[(ky<<2)+kx+2]+u1r[((ky+2)<<2)+kx+2];
      float ii= u1i[(ky<<2)+kx]+u1i[((ky+2)<<2)+kx]+u1i[(ky<<2)+kx+2]+u1i[((ky+2)<<2)+kx+2];
      UR[t*8+c]=r; UI[t*8+c]=ii; }
    return;
  }
  if (bid < PRE_LAT){
    // paired antisymmetrize: tiles (i,j) and (j,i) from one load pair
    int bid2 = bid - PRE_UGEN;
    int m = bid2/15, tl = bid2%15;
    int i64 = p_i[tl]*64, j64 = p_j[tl]*64;
    const float* Lm = L + (size_t)m*CTOT*CTOT;
    float* A = shm;          // 64x65: L[j-rows][i-cols]
    float* B = shm + 4160;   // 64x65: L[i-rows][j-cols]
    bool diag = (i64==j64);
    for (int i=t;i<4096;i+=256){
      int r=i>>6, c=i&63;
      A[r*65+c] = (j64+r<CTOT && i64+c<CTOT) ? Lm[(size_t)(j64+r)*CTOT + i64+c] : 0.f;
      if (!diag)
        B[r*65+c] = (i64+r<CTOT && j64+c<CTOT) ? Lm[(size_t)(i64+r)*CTOT + j64+c] : 0.f;
    }
    __syncthreads();
    float* out = ws + OFF_LAT + (size_t)m*CTOT*CTOT;
    if (diag){
      for (int i=t;i<4096;i+=256){
        int r=i>>6, c=i&63;
        if (i64+r<CTOT && j64+c<CTOT)
          out[(size_t)(i64+r)*CTOT + j64+c] = A[c*65+r] - A[r*65+c];
      }
    } else {
      for (int i=t;i<4096;i+=256){
        int r=i>>6, c=i&63;
        if (i64+r<CTOT && j64+c<CTOT)
          out[(size_t)(i64+r)*CTOT + j64+c] = A[c*65+r] - B[r*65+c];
        if (j64+r<CTOT && i64+c<CTOT)
          out[(size_t)(j64+r)*CTOT + i64+c] = B[c*65+r] - A[r*65+c];
      }
    }
    return;
  }
  if (bid < PRE_LAMF){
    float* sA = shm;
    float* f3 = shm + 1024;
    float* f2 = shm + 1280;
    float* f1 = shm + 1344;
    int m = bid - PRE_LAT;
    for (int k=t;k<1024;k+=256){
      int ky=k>>5, kx=k&31;
      int nk = (((32-ky)&31)<<5) | ((32-kx)&31);
      float v = lam[(m<<10)+k] - lam[(m<<10)+nk];
      sA[k]=v;
      ws[OFF_LAM+(m<<10)+k]=v;
    }
    __syncthreads();
    { int s=t; int ky=s>>4, kx=s&15;
      float v = sA[(ky<<5)+kx]+sA[((ky+16)<<5)+kx]+sA[(ky<<5)+kx+16]+sA[((ky+16)<<5)+kx+16];
      f3[s]=v; ws[OFF_LAMF+m*340+84+s]=v; }
    __syncthreads();
    if (t<64){ int ky=t>>3, kx=t&7;
      float v = f3[(ky<<4)+kx]+f3[((ky+8)<<4)+kx]+f3[(ky<<4)+kx+8]+f3[((ky+8)<<4)+kx+8];
      f2[t]=v; ws[OFF_LAMF+m*340+20+t]=v; }
    __syncthreads();
    if (t<16){ int ky=t>>2, kx=t&3;
      float v = f2[(ky<<3)+kx]+f2[((ky+4)<<3)+kx]+f2[(ky<<3)+kx+4]+f2[((ky+4)<<3)+kx+4];
      f1[t]=v; ws[OFF_LAMF+m*340+4+t]=v; }
    __syncthreads();
    if (t<4){ int ky=t>>1, kx=t&1;
      float v = f1[(ky<<2)+kx]+f1[((ky+2)<<2)+kx]+f1[(ky<<2)+kx+2]+f1[((ky+2)<<2)+kx+2];
      ws[OFF_LAMF+m*340+t]=v; }
    return;
  }
  if (bid < PRE_DFT){
    float* sIn = shm;          // 1024
    float* s1r = shm + 1024;   // 1056 (rows padded to h+1)
    float* s1i = shm + 2080;   // 1056
    float* lc  = shm + 3136;   // 32
    float* lsn = shm + 3168;   // 32
    int i0 = bid - PRE_LAMF;
    int which = i0 / (NB*30);
    int rem = i0 % (NB*30);
    int b = rem / 30, j = rem % 30;
    int l = dft_l[j], c0 = dft_c0[j], nc = dft_nc2[j];
    int h = g_hL[l], n = h*h;
    int hp = h+1, n1 = h*hp;
    int mult = 32/h;
    int elems = nc*n;
    const float* src;
    switch (which*5 + l){
      case 0: src=z0; break; case 1: src=z1; break; case 2: src=z2; break;
      case 3: src=z3; break; case 4: src=z4; break;
      case 5: src=w0; break; case 6: src=w1; break; case 7: src=w2; break;
      case 8: src=w3; break; default: src=w4; break;
    }
    for (int i=t;i<elems;i+=256) sIn[i] = src[(b*g_cL[l] + c0)*n + i];
    if (t<32){
      float ang = -6.2831853071795864f * (float)t / 32.0f;
      lc[t] = cosf(ang); lsn[t] = sinf(ang);
    }
    __syncthreads();
    for (int p=t;p<elems;p+=256){
      int p2=p%n, cc=p/n;
      int y=p2/h, kx=p2-y*h;
      float re=0.f, im=0.f;
      for (int x=0;x<h;x++){
        int id = ((kx*x)%h)*mult;
        float v = sIn[cc*n + y*h + x];
        re += v*lc[id]; im += v*lsn[id];
      }
      s1r[cc*n1 + y*hp + kx]=re; s1i[cc*n1 + y*hp + kx]=im;
    }
    __syncthreads();
    float scale = which ? 1.0f/(float)h : 1.0f;
    bool zt = (which==0 && l<4);   // z levels 0-3: write transposed [bin][channel]
    float* outR;
    float* outI;
    if (zt){
      outR = ws + OFF_ZTR + b*6144 + g_zo[l];
      outI = ws + OFF_ZTI + b*6144 + g_zo[l];
    } else {
      outR = ws + (which?OFF_WRE:OFF_ZRE) + b*12288 + g_zo[l] + c0*n;
      outI = ws + (which?OFF_WIM:OFF_ZIM) + b*12288 + g_zo[l] + c0*n;
    }
    for (int p=t;p<elems;p+=256){
      int p2=p%n, cc=p/n;
      int ky=p2/h, kx=p2-(p2/h)*h;
      float re=0.f, im=0.f;
      for (int y=0;y<h;y++){
        int id=((ky*y)%h)*mult;
        float c=lc[id], s=lsn[id];
        float ar=s1r[cc*n1 + y*hp + kx], ai=s1i[cc*n1 + y*hp + kx];
        re += ar*c - ai*s;
        im += ar*s + ai*c;
      }
      int o = zt ? (p2*g_cL[l] + c0 + cc) : p;
      outR[o]=re*scale; outI[o]=im*scale;
    }
    return;
  }
  if (bid < PRE_SWW){
    float* red = shm;
    int b = bid - PRE_DFT;
    const float* ptr[5] = {w0,w1,w2,w3,w4};
    float s = 0.f;
    for (int l=0;l<5;l++){
      int sz = g_cL[l]*g_hL[l]*g_hL[l];
      const float* p = ptr[l] + b*sz;
      for (int i=t;i<sz;i+=256){ float v=p[i]; s += v*v; }
    }
    red[t]=s; __syncthreads();
    for (int o=128;o>0;o>>=1){ if (t<o) red[t]+=red[t+o]; __syncthreads(); }
    if (t==0) ws[OFF_SWW + b] = red[0];
    return;
  }
  int i = (bid - PRE_SWW)*256 + t;
  if (i < NB*NM*NM + NB*NM) ws[OFF_SZZ + i] = 0.f;
}

// hot kernel: transposed-Z float4 loads, transposed-U float4 combine (unchanged)
__global__ void __launch_bounds__(256) k_fold(float* __restrict__ ws){
  __shared__ float smem[6160];
  float* pre   = smem;          // 6x340
  float* pim   = smem + 2040;   // 6x340
  float* sLa   = smem + 4080;   // 6x284 (chain buffers overlay after phase 1)
  float* c64r  = smem + 4080;   // 384
  float* c64i  = smem + 4464;   // 384
  float* c16r  = smem + 4848;   // 96
  float* c16i  = smem + 4944;   // 96
  float* c4r   = smem + 5040;   // 24
  float* c4i   = smem + 5064;   // 24
  float* lamf  = smem + 5784;   // 340
  float* ssla  = smem + 6124;   // 36

  int t = threadIdx.x, bid = blockIdx.x;
  int m    = bid / (NB*48);
  int rem  = bid % (NB*48);
  int b    = rem / 48;
  int tile = rem % 48;
  int lo = t_lo[tile], d0 = t_d0[tile], nd = t_nd[tile];
  int ho = g_hL[lo];
  int nbins = ho*ho;
  const float* zreb = ws + OFF_ZRE + b*12288;
  const float* zimb = ws + OFF_ZIM + b*12288;
  const float* ztr  = ws + OFF_ZTR + b*6144;
  const float* zti  = ws + OFF_ZTI + b*6144;
  const float* latm = ws + OFF_LAT + (size_t)m*CTOT*CTOT;

  for (int i=t;i<340;i+=256) lamf[i] = ws[OFF_LAMF + m*340 + i];
  for (int i=t;i<nd*282;i+=256){ int d=i/282, c=i-d*282; sLa[d*284+c] = latm[(size_t)(d0+d)*CTOT + c]; }
  if (t<nd*6){ int d=t/6, c=t-d*6; ssla[t] = latm[(size_t)(d0+d)*CTOT + 276 + c]; }

  int lA, kkA, c0A, offP; bool wrt;
  if (t<64){ lA=0; kkA=t&3; c0A=(t>>2)*12; offP=0; wrt=(t<4); }
  else if (t<128){ int i=t-64; lA=1; kkA=i&15; c0A=(i>>4)*12; offP=4; wrt=(i<16); }
  else { int i=t-128; lA=2; kkA=i>>1; c0A=(i&1)*12; offP=20; wrt=((i&1)==0); }
  float zAr[12], zAi[12], zBr[12], zBi[12];
  {
    int oA = g_zo[lA] + kkA*g_cL[lA] + c0A;
    const float4* zr4 = (const float4*)(ztr + oA);
    const float4* zi4 = (const float4*)(zti + oA);
    float4 x0=zr4[0], x1=zr4[1], x2=zr4[2];
    float4 y0=zi4[0], y1=zi4[1], y2=zi4[2];
    zAr[0]=x0.x;zAr[1]=x0.y;zAr[2]=x0.z;zAr[3]=x0.w;zAr[4]=x1.x;zAr[5]=x1.y;zAr[6]=x1.z;zAr[7]=x1.w;zAr[8]=x2.x;zAr[9]=x2.y;zAr[10]=x2.z;zAr[11]=x2.w;
    zAi[0]=y0.x;zAi[1]=y0.y;zAi[2]=y0.z;zAi[3]=y0.w;zAi[4]=y1.x;zAi[5]=y1.y;zAi[6]=y1.z;zAi[7]=y1.w;zAi[8]=y2.x;zAi[9]=y2.y;zAi[10]=y2.z;zAi[11]=y2.w;
    int oB = 3072 + t*12;
    const float4* zr3 = (const float4*)(ztr + oB);
    const float4* zi3 = (const float4*)(zti + oB);
    float4 p0=zr3[0], p1=zr3[1], p2=zr3[2];
    float4 q0=zi3[0], q1=zi3[1], q2=zi3[2];
    zBr[0]=p0.x;zBr[1]=p0.y;zBr[2]=p0.z;zBr[3]=p0.w;zBr[4]=p1.x;zBr[5]=p1.y;zBr[6]=p1.z;zBr[7]=p1.w;zBr[8]=p2.x;zBr[9]=p2.y;zBr[10]=p2.z;zBr[11]=p2.w;
    zBi[0]=q0.x;zBi[1]=q0.y;zBi[2]=q0.z;zBi[3]=q0.w;zBi[4]=q1.x;zBi[5]=q1.y;zBi[6]=q1.z;zBi[7]=q1.w;zBi[8]=q2.x;zBi[9]=q2.y;zBi[10]=q2.z;zBi[11]=q2.w;
  }
  __syncthreads();

  int offA = g_coff[lA] + c0A;
  for (int d=0; d<nd; d++){
    const float4* laA = (const float4*)(sLa + d*284 + offA);
    const float4* laB = (const float4*)(sLa + d*284 + 264);
    float4 a0=laA[0], a1=laA[1], a2=laA[2];
    float4 b0=laB[0], b1=laB[1], b2=laB[2];
    float av[12] = {a0.x,a0.y,a0.z,a0.w, a1.x,a1.y,a1.z,a1.w, a2.x,a2.y,a2.z,a2.w};
    float bv[12] = {b0.x,b0.y,b0.z,b0.w, b1.x,b1.y,b1.z,b1.w, b2.x,b2.y,b2.z,b2.w};
    float prA=0.f, piA=0.f, prB=0.f, piB=0.f;
    #pragma unroll
    for (int c=0;c<12;c++){ prA+=av[c]*zAr[c]; piA+=av[c]*zAi[c]; }
    #pragma unroll
    for (int c=0;c<12;c++){ prB+=bv[c]*zBr[c]; piB+=bv[c]*zBi[c]; }
    if (t<64){
      prA += __shfl_xor(prA, 4);  piA += __shfl_xor(piA, 4);
      prA += __shfl_xor(prA, 8);  piA += __shfl_xor(piA, 8);
      prA += __shfl_xor(prA,16);  piA += __shfl_xor(piA,16);
      prA += __shfl_xor(prA,32);  piA += __shfl_xor(piA,32);
    } else if (t<128){
      prA += __shfl_xor(prA,16);  piA += __shfl_xor(piA,16);
      prA += __shfl_xor(prA,32);  piA += __shfl_xor(piA,32);
    } else {
      prA += __shfl_xor(prA, 1);  piA += __shfl_xor(piA, 1);
    }
    if (wrt){ pre[d*340+offP+kkA]=prA; pim[d*340+offP+kkA]=piA; }
    pre[d*340+84+t]=prB; pim[d*340+84+t]=piB;
  }
  __syncthreads();

  float sc = (float)ho/1024.f;
  if (lo==4){
    int dlb = d0 - 276;
    const float* lamA = ws + OFF_LAM + (m<<10);
    float* vRb = ws + OFF_VRE + (size_t)(b*NM+m)*12288 + 6144 + (dlb<<10);
    float* vIb = ws + OFF_VIM + (size_t)(b*NM+m)*12288 + 6144 + (dlb<<10);
    const float* z4r = zreb + 6144;
    const float* z4i = zimb + 6144;
    for (int q=t; q<1024; q+=256){
      int ky=q>>5, kx=q&31;
      int a0=((ky&1)<<1)|(kx&1);
      int a1=4+(((ky&3)<<2)|(kx&3));
      int a2=20+(((ky&7)<<3)|(kx&7));
      int a3=84+(((ky&15)<<4)|(kx&15));
      float zr_[6], zi_[6];
      #pragma unroll
      for (int c=0;c<6;c++){ zr_[c]=z4r[(c<<10)+q]; zi_[c]=z4i[(c<<10)+q]; }
      float lm = lamA[q]*sc;
      for (int d=0; d<nd; d++){
        const float* pd = pre + d*340; const float* qd = pim + d*340;
        float Br = pd[a0]+pd[a1]+pd[a2]+pd[a3];
        float Bi = qd[a0]+qd[a1]+qd[a2]+qd[a3];
        #pragma unroll
        for (int c=0;c<6;c++){ float a=ssla[d*6+c]; Br+=a*zr_[c]; Bi+=a*zi_[c]; }
        vRb[(d<<10)+q] = -lm*Bi;
        vIb[(d<<10)+q] =  lm*Br;
      }
    }
    return;
  }

  if (lo<3){
    for (int idx=t; idx<nd*64; idx+=256){
      int d=idx>>6, k2=idx&63, ky=k2>>3, kx=k2&7;
      const float* pd = pre + d*340 + 84; const float* qd = pim + d*340 + 84;
      float r=0.f, ii=0.f;
      #pragma unroll
      for (int jy=0;jy<2;jy++)
        #pragma unroll
        for (int jx=0;jx<2;jx++){
          int a = ((ky+8*jy)<<4) | (kx+8*jx);
          float f = lamf[84+a];
          r += f*pd[a]; ii += f*qd[a];
        }
      if (lo<2){ float f=lamf[20+k2]; r+=f*pre[d*340+20+k2]; ii+=f*pim[d*340+20+k2]; }
      c64r[idx]=r; c64i[idx]=ii;
    }
  }
  __syncthreads();
  if (lo<2){
    for (int idx=t; idx<nd*16; idx+=256){
      int d=idx>>4, k2=idx&15, ky=k2>>2, kx=k2&3, base=d<<6;
      float r = c64r[base+(ky<<3)+kx]+c64r[base+((ky+4)<<3)+kx]+c64r[base+(ky<<3)+kx+4]+c64r[base+((ky+4)<<3)+kx+4];
      float ii= c64i[base+(ky<<3)+kx]+c64i[base+((ky+4)<<3)+kx]+c64i[base+(ky<<3)+kx+4]+c64i[base+((ky+4)<<3)+kx+4];
      if (lo<1){ float f=lamf[4+k2]; r+=f*pre[d*340+4+k2]; ii+=f*pim[d*340+4+k2]; }
      c16r[idx]=r; c16i[idx]=ii;
    }
  }
  __syncthreads();
  if (lo==0 && t<nd*4){
    int d=t>>2, k2=t&3, ky=k2>>1, kx=k2&1, base=d<<4;
    c4r[t]=c16r[base+(ky<<2)+kx]+c16r[base+((ky+2)<<2)+kx]+c16r[base+(ky<<2)+kx+2]+c16r[base+((ky+2)<<2)+kx+2];
    c4i[t]=c16i[base+(ky<<2)+kx]+c16i[base+((ky+2)<<2)+kx]+c16i[base+(ky<<2)+kx+2]+c16i[base+((ky+2)<<2)+kx+2];
  }
  __syncthreads();

  int dlb = d0 - g_coff[lo];
  float* vRb = ws + OFF_VRE + (size_t)(b*NM+m)*12288 + g_zo[lo];
  float* vIb = ws + OFF_VIM + (size_t)(b*NM+m)*12288 + g_zo[lo];
  const float* URg = ws + OFF_UR + (size_t)(b*NM+m)*2720;
  const float* UIg = ws + OFF_UI + (size_t)(b*NM+m)*2720;
  for (int idx=t; idx<nd*nbins; idx+=256){
    int d=idx/nbins, bin=idx-d*nbins;
    int ky=bin/ho, kx=bin-ky*ho;
    const float* pd = pre + d*340; const float* qd = pim + d*340;
    float Br = pd[((ky&1)<<1)|(kx&1)], Bi = qd[((ky&1)<<1)|(kx&1)];
    if (lo>=1){ int ix=4+(((ky&3)<<2)|(kx&3)); Br+=pd[ix]; Bi+=qd[ix]; }
    if (lo>=2){ int ix=20+(((ky&7)<<3)|(kx&7)); Br+=pd[ix]; Bi+=qd[ix]; }
    if (lo>=3){ int ix=84+(((ky&15)<<4)|(kx&15)); Br+=pd[ix]; Bi+=qd[ix]; }
    float lf = lamf[g_po[lo]+bin];
    float Vr = lf*Br, Vi = lf*Bi;
    if (lo==2){ Vr+=c64r[(d<<6)+bin]; Vi+=c64i[(d<<6)+bin]; }
    else if (lo==1){ Vr+=c16r[(d<<4)+bin]; Vi+=c16i[(d<<4)+bin]; }
    else if (lo==0){ Vr+=c4r[(d<<2)+bin]; Vi+=c4i[(d<<2)+bin]; }
    {
      int e = (g_po[lo]+bin)*8;
      const float4* ur4 = (const float4*)(URg + e);
      const float4* ui4 = (const float4*)(UIg + e);
      float4 u0=ur4[0], u1=ur4[1];
      float4 v0=ui4[0], v1=ui4[1];
      const float* sd = ssla + d*6;
      Vr += sd[0]*u0.x + sd[1]*u0.y + sd[2]*u0.z + sd[3]*u0.w + sd[4]*u1.x + sd[5]*u1.y;
      Vi += sd[0]*v0.x + sd[1]*v0.y + sd[2]*v0.z + sd[3]*v0.w + sd[4]*v1.x + sd[5]*v1.y;
    }
    int ob = (dlb+d)*nbins + bin;
    vRb[ob] = -sc*Vi;
    vIb[ob] =  sc*Vr;
  }
}

// S_zz gram + S_zw: 128-wide k-chunks (768 blocks), float4 loads
__global__ void __launch_bounds__(256) k_gram(float* __restrict__ ws){
  __shared__ float tile[32*132];
  __shared__ float wv[128];
  int t = threadIdx.x;
  int bid = blockIdx.x;
  int b = bid / 192, ch = bid % 192;
  int half = ch / 96;
  int k0 = (ch % 96) * 128;
  const float* V = ws + (half?OFF_VIM:OFF_VRE);
  const float* W = ws + (half?OFF_WIM:OFF_WRE) + b*12288 + k0;
  #pragma unroll
  for (int p=0;p<4;p++){
    int i4 = t + (p<<8);
    int row = i4 >> 5, c4 = i4 & 31;
    float4 v = *(const float4*)(V + (size_t)(b*NM+row)*12288 + k0 + (c4<<2));
    *(float4*)(tile + row*132 + (c4<<2)) = v;
  }
  if (t<128) wv[t] = W[t];
  __syncthreads();
  const float4* tf = (const float4*)tile;
  int n0 = t>>5, mm = t&31;
  float acc0=0.f, acc1=0.f, acc2=0.f, acc3=0.f;
  const float4* rm = tf + mm*33;
  const float4* r0 = tf + n0*33;
  const float4* r1 = tf + (n0+8)*33;
  const float4* r2 = tf + (n0+16)*33;
  const float4* r3 = tf + (n0+24)*33;
  for (int k4=0;k4<32;k4++){
    float4 vm = rm[k4];
    float4 v0 = r0[k4];
    float4 v1 = r1[k4];
    float4 v2 = r2[k4];
    float4 v3 = r3[k4];
    acc0 += v0.x*vm.x + v0.y*vm.y + v0.z*vm.z + v0.w*vm.w;
    acc1 += v1.x*vm.x + v1.y*vm.y + v1.z*vm.z + v1.w*vm.w;
    acc2 += v2.x*vm.x + v2.y*vm.y + v2.z*vm.z + v2.w*vm.w;
    acc3 += v3.x*vm.x + v3.y*vm.y + v3.z*vm.z + v3.w*vm.w;
  }
  float* szz = ws + OFF_SZZ + (b<<10);
  atomicAdd(&szz[(n0<<5) + mm], acc0);
  atomicAdd(&szz[((n0+8)<<5) + mm], acc1);
  atomicAdd(&szz[((n0+16)<<5) + mm], acc2);
  atomicAdd(&szz[((n0+24)<<5) + mm], acc3);
  if (t < 32){
    const float4* rn = tf + t*33;
    const float4* wf = (const float4*)wv;
    float acc=0.f;
    for (int k4=0;k4<32;k4++){
      float4 a = rn[k4]; float4 wq = wf[k4];
      acc += a.x*wq.x + a.y*wq.y + a.z*wq.z + a.w*wq.w;
    }
    atomicAdd(&ws[OFF_SZW + (b<<5) + t], acc);
  }
}

// var, normalize, Cholesky 32x32 in LDS, logdet, trace, output
__global__ void k_final(float* __restrict__ ws, float* __restrict__ out){
  __shared__ float A[32][33];
  __shared__ float svar;
  int b = blockIdx.x, t = threadIdx.x;
  const float* szz = ws + OFF_SZZ + (b<<10);
  if (t==0){
    float s=0.f;
    for (int i=0;i<32;i++) s += szz[i*33];
    svar = fmaxf(s/32.0f, 1e-6f);
  }
  __syncthreads();
  float var = svar;
  for (int i=t;i<1024;i+=64){
    int r=i>>5, c=i&31;
    A[r][c] = szz[i]/var + ((r==c)?EPSV:0.0f);
  }
  __syncthreads();
  for (int j=0;j<32;j++){
    if (t==0) A[j][j] = sqrtf(A[j][j]);
    __syncthreads();
    if (t>j && t<32) A[t][j] /= A[j][j];
    __syncthreads();
    if (t>j && t<32){
      float lij = A[t][j];
      for (int k=j+1;k<=t;k++) A[t][k] -= lij*A[k][j];
    }
    __syncthreads();
  }
  if (t==0){
    float logdet=0.f;
    for (int j=0;j<32;j++) logdet += logf(A[j][j]);
    logdet *= 2.0f;
    const float* szw = ws + OFF_SZW + (b<<5);
    float s2=0.f;
    for (int n=0;n<32;n++) s2 += szw[n]*szw[n];
    float trace = EPSV*ws[OFF_SWW + b] + s2/var;
    out[b] = 0.5f*(logdet - trace);
  }
}

extern "C" void kernel_launch(void* const* d_in, const int* in_sizes, int n_in,
                              void* d_out, int out_size, void* d_ws, size_t ws_size,
                              hipStream_t stream){
  // setup_inputs() dict order is INTERLEAVED: z0,w0,z1,w1,z2,w2,z3,w3,z4,w4,L,lam
  const float* z0 = (const float*)d_in[0];
  const float* w0 = (const float*)d_in[1];
  const float* z1 = (const float*)d_in[2];
  const float* w1 = (const float*)d_in[3];
  const float* z2 = (const float*)d_in[4];
  const float* w2 = (const float*)d_in[5];
  const float* z3 = (const float*)d_in[6];
  const float* w3 = (const float*)d_in[7];
  const float* z4 = (const float*)d_in[8];
  const float* w4 = (const float*)d_in[9];
  const float* L   = (const float*)d_in[10];
  const float* lam = (const float*)d_in[11];
  float* ws = (float*)d_ws;
  float* out = (float*)d_out;

  k_pre<<<PRE_TOT, 256, 0, stream>>>(z0,z1,z2,z3,z4,w0,w1,w2,w3,w4, L, lam, ws);
  k_fold<<<NB*NM*48, 256, 0, stream>>>(ws);
  k_gram<<<NB*192, 256, 0, stream>>>(ws);
  k_final<<<NB, 64, 0, stream>>>(ws, out);
}

// Round 13
// 195.065 us; speedup vs baseline: 1.0629x; 1.0629x over previous
//
#include <hip/hip_runtime.h>
#include <math.h>

#define NB 4
#define NM 32
#define CTOT 282
#define EPSV 1e-3f

__constant__ int g_cL[5]   = {192,48,24,12,6};
__constant__ int g_hL[5]   = {2,4,8,16,32};
__constant__ int g_coff[5] = {0,192,240,264,276};
__constant__ int g_zo[5]   = {0,768,1536,3072,6144};
__constant__ int g_po[4]   = {0,4,20,84};

// 48 level-homogeneous d-tiles
__constant__ int t_lo[48] = {0,0,0,0,0,0,0,0,0,0,0,0,0,0,0,0,
                             0,0,0,0,0,0,0,0,0,0,0,0,0,0,0,0,
                             1,1,1,1,1,1,1,1, 2,2,2,2, 3,3, 4,4};
__constant__ int t_d0[48] = {0,6,12,18,24,30,36,42,48,54,60,66,72,78,84,90,
                             96,102,108,114,120,126,132,138,144,150,156,162,168,174,180,186,
                             192,198,204,210,216,222,228,234, 240,246,252,258, 264,270, 276,279};
__constant__ int t_nd[48] = {6,6,6,6,6,6,6,6,6,6,6,6,6,6,6,6,
                             6,6,6,6,6,6,6,6,6,6,6,6,6,6,6,6,
                             6,6,6,6,6,6,6,6, 6,6,6,6, 6,6, 3,3};

// dft sub-block tables (30 per (which,b)): level + channel offset
__constant__ int dft_l[30]  = {0,0,0, 1,1,1, 2,2,2,2,2,2,
                               3,3,3,3,3,3,3,3,3,3,3,3, 4,4,4,4,4,4};
__constant__ int dft_c0[30] = {0,64,128, 0,16,32, 0,4,8,12,16,20,
                               0,1,2,3,4,5,6,7,8,9,10,11, 0,1,2,3,4,5};
__constant__ int dft_nc2[30] = {64,64,64, 16,16,16, 4,4,4,4,4,4,
                                1,1,1,1,1,1,1,1,1,1,1,1, 1,1,1,1,1,1};

// LAT tile pairs (i<=j), 15 per m
__constant__ int p_i[15] = {0,0,0,0,0,1,1,1,1,2,2,2,3,3,4};
__constant__ int p_j[15] = {0,1,2,3,4,1,2,3,4,2,3,4,3,4,4};

// workspace layout (float offsets)
#define N_LA     (NM*CTOT*CTOT)
#define OFF_LAT  0
#define OFF_ZRE  (OFF_LAT + N_LA)
#define OFF_ZIM  (OFF_ZRE + NB*12288)
#define OFF_WRE  (OFF_ZIM + NB*12288)
#define OFF_WIM  (OFF_WRE + NB*12288)
#define OFF_LAM  (OFF_WIM + NB*12288)
#define OFF_LAMF (OFF_LAM + NM*1024)
#define OFF_ZTR  (OFF_LAMF + NM*340)
#define OFF_ZTI  (OFF_ZTR + NB*6144)
#define OFF_UR   (OFF_ZTI + NB*6144)
#define OFF_UI   (OFF_UR + NB*NM*2720)
#define OFF_VRE  (OFF_UI + NB*NM*2720)
#define OFF_VIM  (OFF_VRE + NB*NM*12288)
#define OFF_SZZ  (OFF_VIM + NB*NM*12288)
#define OFF_SZW  (OFF_SZZ + NB*NM*NM)
#define OFF_SWW  (OFF_SZW + NB*NM)

// k_pre bid ranges (R11 order: UGEN at tail; now 192 blocks x 4-m loop)
#define PRE_LAT   (NM*15)              /* 480 */
#define PRE_LAMF  (PRE_LAT + NM)       /* +32  -> 512 */
#define PRE_DFT   (PRE_LAMF + 2*NB*30) /* +240 -> 752 */
#define PRE_SWW   (PRE_DFT + NB)       /* +4   -> 756 */
#define PRE_ZERO  (PRE_SWW + 17)       /* +17  -> 773 */
#define PRE_UGEN  (PRE_ZERO + 192)     /* +192 -> 965 */

// merged: paired LaT + lamA/lamfold + DFTs (z0-3 transposed) + S_ww + SZZ zero + UGEN (tail)
__global__ void __launch_bounds__(256) k_pre(
    const float* z0,const float* z1,const float* z2,const float* z3,const float* z4,
    const float* w0,const float* w1,const float* w2,const float* w3,const float* w4,
    const float* __restrict__ L, const float* __restrict__ lam, float* __restrict__ ws){
  __shared__ float shm[8320];
  int bid = blockIdx.x, t = threadIdx.x;
  if (bid < PRE_LAT){
    // paired antisymmetrize: tiles (i,j) and (j,i) from one load pair
    int m = bid/15, tl = bid%15;
    int i64 = p_i[tl]*64, j64 = p_j[tl]*64;
    const float* Lm = L + (size_t)m*CTOT*CTOT;
    float* A = shm;          // 64x65: L[j-rows][i-cols]
    float* B = shm + 4160;   // 64x65: L[i-rows][j-cols]
    bool diag = (i64==j64);
    for (int i=t;i<4096;i+=256){
      int r=i>>6, c=i&63;
      A[r*65+c] = (j64+r<CTOT && i64+c<CTOT) ? Lm[(size_t)(j64+r)*CTOT + i64+c] : 0.f;
      if (!diag)
        B[r*65+c] = (i64+r<CTOT && j64+c<CTOT) ? Lm[(size_t)(i64+r)*CTOT + j64+c] : 0.f;
    }
    __syncthreads();
    float* out = ws + OFF_LAT + (size_t)m*CTOT*CTOT;
    if (diag){
      for (int i=t;i<4096;i+=256){
        int r=i>>6, c=i&63;
        if (i64+r<CTOT && j64+c<CTOT)
          out[(size_t)(i64+r)*CTOT + j64+c] = A[c*65+r] - A[r*65+c];
      }
    } else {
      for (int i=t;i<4096;i+=256){
        int r=i>>6, c=i&63;
        if (i64+r<CTOT && j64+c<CTOT)
          out[(size_t)(i64+r)*CTOT + j64+c] = A[c*65+r] - B[r*65+c];
        if (j64+r<CTOT && i64+c<CTOT)
          out[(size_t)(j64+r)*CTOT + i64+c] = B[c*65+r] - A[r*65+c];
      }
    }
    return;
  }
  if (bid < PRE_LAMF){
    float* sA = shm;
    float* f3 = shm + 1024;
    float* f2 = shm + 1280;
    float* f1 = shm + 1344;
    int m = bid - PRE_LAT;
    for (int k=t;k<1024;k+=256){
      int ky=k>>5, kx=k&31;
      int nk = (((32-ky)&31)<<5) | ((32-kx)&31);
      float v = lam[(m<<10)+k] - lam[(m<<10)+nk];
      sA[k]=v;
      ws[OFF_LAM+(m<<10)+k]=v;
    }
    __syncthreads();
    { int s=t; int ky=s>>4, kx=s&15;
      float v = sA[(ky<<5)+kx]+sA[((ky+16)<<5)+kx]+sA[(ky<<5)+kx+16]+sA[((ky+16)<<5)+kx+16];
      f3[s]=v; ws[OFF_LAMF+m*340+84+s]=v; }
    __syncthreads();
    if (t<64){ int ky=t>>3, kx=t&7;
      float v = f3[(ky<<4)+kx]+f3[((ky+8)<<4)+kx]+f3[(ky<<4)+kx+8]+f3[((ky+8)<<4)+kx+8];
      f2[t]=v; ws[OFF_LAMF+m*340+20+t]=v; }
    __syncthreads();
    if (t<16){ int ky=t>>2, kx=t&3;
      float v = f2[(ky<<3)+kx]+f2[((ky+4)<<3)+kx]+f2[(ky<<3)+kx+4]+f2[((ky+4)<<3)+kx+4];
      f1[t]=v; ws[OFF_LAMF+m*340+4+t]=v; }
    __syncthreads();
    if (t<4){ int ky=t>>1, kx=t&1;
      float v = f1[(ky<<2)+kx]+f1[((ky+2)<<2)+kx]+f1[(ky<<2)+kx+2]+f1[((ky+2)<<2)+kx+2];
      ws[OFF_LAMF+m*340+t]=v; }
    return;
  }
  if (bid < PRE_DFT){
    float* sIn = shm;          // 1024
    float* s1r = shm + 1024;   // 1056 (rows padded to h+1)
    float* s1i = shm + 2080;   // 1056
    float* lc  = shm + 3136;   // 32
    float* lsn = shm + 3168;   // 32
    int i0 = bid - PRE_LAMF;
    int which = i0 / (NB*30);
    int rem = i0 % (NB*30);
    int b = rem / 30, j = rem % 30;
    int l = dft_l[j], c0 = dft_c0[j], nc = dft_nc2[j];
    int h = g_hL[l], n = h*h;
    int hp = h+1, n1 = h*hp;
    int mult = 32/h;
    int elems = nc*n;
    const float* src;
    switch (which*5 + l){
      case 0: src=z0; break; case 1: src=z1; break; case 2: src=z2; break;
      case 3: src=z3; break; case 4: src=z4; break;
      case 5: src=w0; break; case 6: src=w1; break; case 7: src=w2; break;
      case 8: src=w3; break; default: src=w4; break;
    }
    for (int i=t;i<elems;i+=256) sIn[i] = src[(b*g_cL[l] + c0)*n + i];
    if (t<32){
      float ang = -6.2831853071795864f * (float)t / 32.0f;
      lc[t] = cosf(ang); lsn[t] = sinf(ang);
    }
    __syncthreads();
    for (int p=t;p<elems;p+=256){
      int p2=p%n, cc=p/n;
      int y=p2/h, kx=p2-y*h;
      float re=0.f, im=0.f;
      for (int x=0;x<h;x++){
        int id = ((kx*x)%h)*mult;
        float v = sIn[cc*n + y*h + x];
        re += v*lc[id]; im += v*lsn[id];
      }
      s1r[cc*n1 + y*hp + kx]=re; s1i[cc*n1 + y*hp + kx]=im;
    }
    __syncthreads();
    float scale = which ? 1.0f/(float)h : 1.0f;
    bool zt = (which==0 && l<4);   // z levels 0-3: write transposed [bin][channel]
    float* outR;
    float* outI;
    if (zt){
      outR = ws + OFF_ZTR + b*6144 + g_zo[l];
      outI = ws + OFF_ZTI + b*6144 + g_zo[l];
    } else {
      outR = ws + (which?OFF_WRE:OFF_ZRE) + b*12288 + g_zo[l] + c0*n;
      outI = ws + (which?OFF_WIM:OFF_ZIM) + b*12288 + g_zo[l] + c0*n;
    }
    for (int p=t;p<elems;p+=256){
      int p2=p%n, cc=p/n;
      int ky=p2/h, kx=p2-(p2/h)*h;
      float re=0.f, im=0.f;
      for (int y=0;y<h;y++){
        int id=((ky*y)%h)*mult;
        float c=lc[id], s=lsn[id];
        float ar=s1r[cc*n1 + y*hp + kx], ai=s1i[cc*n1 + y*hp + kx];
        re += ar*c - ai*s;
        im += ar*s + ai*c;
      }
      int o = zt ? (p2*g_cL[l] + c0 + cc) : p;
      outR[o]=re*scale; outI[o]=im*scale;
    }
    return;
  }
  if (bid < PRE_SWW){
    float* red = shm;
    int b = bid - PRE_DFT;
    const float* ptr[5] = {w0,w1,w2,w3,w4};
    float s = 0.f;
    for (int l=0;l<5;l++){
      int sz = g_cL[l]*g_hL[l]*g_hL[l];
      const float* p = ptr[l] + b*sz;
      for (int i=t;i<sz;i+=256){ float v=p[i]; s += v*v; }
    }
    red[t]=s; __syncthreads();
    for (int o=128;o>0;o>>=1){ if (t<o) red[t]+=red[t+o]; __syncthreads(); }
    if (t==0) ws[OFF_SWW + b] = red[0];
    return;
  }
  if (bid < PRE_ZERO){
    int i = (bid - PRE_SWW)*256 + t;
    if (i < NB*NM*NM + NB*NM) ws[OFF_SZZ + i] = 0.f;
    return;
  }
  // UGEN (tail): (b, c4, m-group-of-4). One shared z4 DFT per block + 4-m fold loop.
  {
    float* sIn = shm;          // 1024
    float* s1r = shm + 1024;   // 1056
    float* s1i = shm + 2080;   // 1056
    float* zr  = shm + 3136;   // 1024
    float* zi  = shm + 4160;   // 1024
    float* lc  = shm + 5184;   // 32
    float* lsn = shm + 5216;   // 32
    float* u3r = shm + 5248;   // 256
    float* u3i = shm + 5504;   // 256
    float* u2r = shm + 5760;   // 64
    float* u2i = shm + 5824;   // 64
    float* u1r = shm + 5888;   // 16
    float* u1i = shm + 5904;   // 16
    int idx = bid - PRE_ZERO;
    int b = idx/48; int r2 = idx%48; int c = r2/8; int mg = r2%8;
    const float* src = z4 + (b*6 + c)*1024;
    for (int i=t;i<1024;i+=256) sIn[i]=src[i];
    if (t<32){
      float ang = -6.2831853071795864f * (float)t / 32.0f;
      lc[t]=cosf(ang); lsn[t]=sinf(ang);
    }
    __syncthreads();
    for (int p=t;p<1024;p+=256){
      int y=p>>5, kx=p&31;
      float re=0.f, im=0.f;
      for (int x=0;x<32;x++){
        int id=(kx*x)&31;
        float v=sIn[(y<<5)+x];
        re += v*lc[id]; im += v*lsn[id];
      }
      s1r[y*33+kx]=re; s1i[y*33+kx]=im;
    }
    __syncthreads();
    for (int p=t;p<1024;p+=256){
      int ky=p>>5, kx=p&31;
      float re=0.f, im=0.f;
      for (int y=0;y<32;y++){
        int id=(ky*y)&31;
        float cc=lc[id], ss=lsn[id];
        float ar=s1r[y*33+kx], ai=s1i[y*33+kx];
        re += ar*cc - ai*ss;
        im += ar*ss + ai*cc;
      }
      zr[p]=re; zi[p]=im;
    }
    __syncthreads();
    for (int mi=0; mi<4; mi++){
      int m = mg*4 + mi;
      const float* lm = lam + (m<<10);
      size_t base = (size_t)(b*NM+m)*2720;
      float* UR = ws+OFF_UR+base; float* UI = ws+OFF_UI+base;
      {
        int sy=t>>4, sx=t&15;
        float ur=0.f, ui=0.f;
        #pragma unroll
        for (int jy=0;jy<2;jy++)
          #pragma unroll
          for (int jx=0;jx<2;jx++){
            int ky=sy+16*jy, kx=sx+16*jx;
            int k=(ky<<5)|kx;
            int nk=(((32-ky)&31)<<5)|((32-kx)&31);
            float la = lm[k]-lm[nk];
            ur += la*zr[k]; ui += la*zi[k];
          }
        u3r[t]=ur; u3i[t]=ui;
        UR[(84+t)*8+c]=ur; UI[(84+t)*8+c]=ui;
      }
      __syncthreads();
      if (t<64){ int ky=t>>3, kx=t&7;
        float r = u3r[(ky<<4)+kx]+u3r[((ky+8)<<4)+kx]+u3r[(ky<<4)+kx+8]+u3r[((ky+8)<<4)+kx+8];
        float ii= u3i[(ky<<4)+kx]+u3i[((ky+8)<<4)+kx]+u3i[(ky<<4)+kx+8]+u3i[((ky+8)<<4)+kx+8];
        u2r[t]=r; u2i[t]=ii; UR[(20+t)*8+c]=r; UI[(20+t)*8+c]=ii; }
      __syncthreads();
      if (t<16){ int ky=t>>2, kx=t&3;
        float r = u2r[(ky<<3)+kx]+u2r[((ky+4)<<3)+kx]+u2r[(ky<<3)+kx+4]+u2r[((ky+4)<<3)+kx+4];
        float ii= u2i[(ky<<3)+kx]+u2i[((ky+4)<<3)+kx]+u2i[(ky<<3)+kx+4]+u2i[((ky+4)<<3)+kx+4];
        u1r[t]=r; u1i[t]=ii; UR[(4+t)*8+c]=r; UI[(4+t)*8+c]=ii; }
      __syncthreads();
      if (t<4){ int ky=t>>1, kx=t&1;
        float r = u1r[(ky<<2)+kx]+u1r[((ky+2)<<2)+kx]+u1r[(ky<<2)+kx+2]+u1r[((ky+2)<<2)+kx+2];
        float ii= u1i[(ky<<2)+kx]+u1i[((ky+2)<<2)+kx]+u1i[(ky<<2)+kx+2]+u1i[((ky+2)<<2)+kx+2];
        UR[t*8+c]=r; UI[t*8+c]=ii; }
      __syncthreads();
    }
  }
}

// hot kernel: transposed-Z float4 loads, transposed-U float4 combine (unchanged)
__global__ void __launch_bounds__(256) k_fold(float* __restrict__ ws){
  __shared__ float smem[6160];
  float* pre   = smem;          // 6x340
  float* pim   = smem + 2040;   // 6x340
  float* sLa   = smem + 4080;   // 6x284 (chain buffers overlay after phase 1)
  float* c64r  = smem + 4080;   // 384
  float* c64i  = smem + 4464;   // 384
  float* c16r  = smem + 4848;   // 96
  float* c16i  = smem + 4944;   // 96
  float* c4r   = smem + 5040;   // 24
  float* c4i   = smem + 5064;   // 24
  float* lamf  = smem + 5784;   // 340
  float* ssla  = smem + 6124;   // 36

  int t = threadIdx.x, bid = blockIdx.x;
  int m    = bid / (NB*48);
  int rem  = bid % (NB*48);
  int b    = rem / 48;
  int tile = rem % 48;
  int lo = t_lo[tile], d0 = t_d0[tile], nd = t_nd[tile];
  int ho = g_hL[lo];
  int nbins = ho*ho;
  const float* zreb = ws + OFF_ZRE + b*12288;
  const float* zimb = ws + OFF_ZIM + b*12288;
  const float* ztr  = ws + OFF_ZTR + b*6144;
  const float* zti  = ws + OFF_ZTI + b*6144;
  const float* latm = ws + OFF_LAT + (size_t)m*CTOT*CTOT;

  for (int i=t;i<340;i+=256) lamf[i] = ws[OFF_LAMF + m*340 + i];
  for (int i=t;i<nd*282;i+=256){ int d=i/282, c=i-d*282; sLa[d*284+c] = latm[(size_t)(d0+d)*CTOT + c]; }
  if (t<nd*6){ int d=t/6, c=t-d*6; ssla[t] = latm[(size_t)(d0+d)*CTOT + 276 + c]; }

  int lA, kkA, c0A, offP; bool wrt;
  if (t<64){ lA=0; kkA=t&3; c0A=(t>>2)*12; offP=0; wrt=(t<4); }
  else if (t<128){ int i=t-64; lA=1; kkA=i&15; c0A=(i>>4)*12; offP=4; wrt=(i<16); }
  else { int i=t-128; lA=2; kkA=i>>1; c0A=(i&1)*12; offP=20; wrt=((i&1)==0); }
  float zAr[12], zAi[12], zBr[12], zBi[12];
  {
    int oA = g_zo[lA] + kkA*g_cL[lA] + c0A;
    const float4* zr4 = (const float4*)(ztr + oA);
    const float4* zi4 = (const float4*)(zti + oA);
    float4 x0=zr4[0], x1=zr4[1], x2=zr4[2];
    float4 y0=zi4[0], y1=zi4[1], y2=zi4[2];
    zAr[0]=x0.x;zAr[1]=x0.y;zAr[2]=x0.z;zAr[3]=x0.w;zAr[4]=x1.x;zAr[5]=x1.y;zAr[6]=x1.z;zAr[7]=x1.w;zAr[8]=x2.x;zAr[9]=x2.y;zAr[10]=x2.z;zAr[11]=x2.w;
    zAi[0]=y0.x;zAi[1]=y0.y;zAi[2]=y0.z;zAi[3]=y0.w;zAi[4]=y1.x;zAi[5]=y1.y;zAi[6]=y1.z;zAi[7]=y1.w;zAi[8]=y2.x;zAi[9]=y2.y;zAi[10]=y2.z;zAi[11]=y2.w;
    int oB = 3072 + t*12;
    const float4* zr3 = (const float4*)(ztr + oB);
    const float4* zi3 = (const float4*)(zti + oB);
    float4 p0=zr3[0], p1=zr3[1], p2=zr3[2];
    float4 q0=zi3[0], q1=zi3[1], q2=zi3[2];
    zBr[0]=p0.x;zBr[1]=p0.y;zBr[2]=p0.z;zBr[3]=p0.w;zBr[4]=p1.x;zBr[5]=p1.y;zBr[6]=p1.z;zBr[7]=p1.w;zBr[8]=p2.x;zBr[9]=p2.y;zBr[10]=p2.z;zBr[11]=p2.w;
    zBi[0]=q0.x;zBi[1]=q0.y;zBi[2]=q0.z;zBi[3]=q0.w;zBi[4]=q1.x;zBi[5]=q1.y;zBi[6]=q1.z;zBi[7]=q1.w;zBi[8]=q2.x;zBi[9]=q2.y;zBi[10]=q2.z;zBi[11]=q2.w;
  }
  __syncthreads();

  int offA = g_coff[lA] + c0A;
  for (int d=0; d<nd; d++){
    const float4* laA = (const float4*)(sLa + d*284 + offA);
    const float4* laB = (const float4*)(sLa + d*284 + 264);
    float4 a0=laA[0], a1=laA[1], a2=laA[2];
    float4 b0=laB[0], b1=laB[1], b2=laB[2];
    float av[12] = {a0.x,a0.y,a0.z,a0.w, a1.x,a1.y,a1.z,a1.w, a2.x,a2.y,a2.z,a2.w};
    float bv[12] = {b0.x,b0.y,b0.z,b0.w, b1.x,b1.y,b1.z,b1.w, b2.x,b2.y,b2.z,b2.w};
    float prA=0.f, piA=0.f, prB=0.f, piB=0.f;
    #pragma unroll
    for (int c=0;c<12;c++){ prA+=av[c]*zAr[c]; piA+=av[c]*zAi[c]; }
    #pragma unroll
    for (int c=0;c<12;c++){ prB+=bv[c]*zBr[c]; piB+=bv[c]*zBi[c]; }
    if (t<64){
      prA += __shfl_xor(prA, 4);  piA += __shfl_xor(piA, 4);
      prA += __shfl_xor(prA, 8);  piA += __shfl_xor(piA, 8);
      prA += __shfl_xor(prA,16);  piA += __shfl_xor(piA,16);
      prA += __shfl_xor(prA,32);  piA += __shfl_xor(piA,32);
    } else if (t<128){
      prA += __shfl_xor(prA,16);  piA += __shfl_xor(piA,16);
      prA += __shfl_xor(prA,32);  piA += __shfl_xor(piA,32);
    } else {
      prA += __shfl_xor(prA, 1);  piA += __shfl_xor(piA, 1);
    }
    if (wrt){ pre[d*340+offP+kkA]=prA; pim[d*340+offP+kkA]=piA; }
    pre[d*340+84+t]=prB; pim[d*340+84+t]=piB;
  }
  __syncthreads();

  float sc = (float)ho/1024.f;
  if (lo==4){
    int dlb = d0 - 276;
    const float* lamA = ws + OFF_LAM + (m<<10);
    float* vRb = ws + OFF_VRE + (size_t)(b*NM+m)*12288 + 6144 + (dlb<<10);
    float* vIb = ws + OFF_VIM + (size_t)(b*NM+m)*12288 + 6144 + (dlb<<10);
    const float* z4r = zreb + 6144;
    const float* z4i = zimb + 6144;
    for (int q=t; q<1024; q+=256){
      int ky=q>>5, kx=q&31;
      int a0=((ky&1)<<1)|(kx&1);
      int a1=4+(((ky&3)<<2)|(kx&3));
      int a2=20+(((ky&7)<<3)|(kx&7));
      int a3=84+(((ky&15)<<4)|(kx&15));
      float zr_[6], zi_[6];
      #pragma unroll
      for (int c=0;c<6;c++){ zr_[c]=z4r[(c<<10)+q]; zi_[c]=z4i[(c<<10)+q]; }
      float lm = lamA[q]*sc;
      for (int d=0; d<nd; d++){
        const float* pd = pre + d*340; const float* qd = pim + d*340;
        float Br = pd[a0]+pd[a1]+pd[a2]+pd[a3];
        float Bi = qd[a0]+qd[a1]+qd[a2]+qd[a3];
        #pragma unroll
        for (int c=0;c<6;c++){ float a=ssla[d*6+c]; Br+=a*zr_[c]; Bi+=a*zi_[c]; }
        vRb[(d<<10)+q] = -lm*Bi;
        vIb[(d<<10)+q] =  lm*Br;
      }
    }
    return;
  }

  if (lo<3){
    for (int idx=t; idx<nd*64; idx+=256){
      int d=idx>>6, k2=idx&63, ky=k2>>3, kx=k2&7;
      const float* pd = pre + d*340 + 84; const float* qd = pim + d*340 + 84;
      float r=0.f, ii=0.f;
      #pragma unroll
      for (int jy=0;jy<2;jy++)
        #pragma unroll
        for (int jx=0;jx<2;jx++){
          int a = ((ky+8*jy)<<4) | (kx+8*jx);
          float f = lamf[84+a];
          r += f*pd[a]; ii += f*qd[a];
        }
      if (lo<2){ float f=lamf[20+k2]; r+=f*pre[d*340+20+k2]; ii+=f*pim[d*340+20+k2]; }
      c64r[idx]=r; c64i[idx]=ii;
    }
  }
  __syncthreads();
  if (lo<2){
    for (int idx=t; idx<nd*16; idx+=256){
      int d=idx>>4, k2=idx&15, ky=k2>>2, kx=k2&3, base=d<<6;
      float r = c64r[base+(ky<<3)+kx]+c64r[base+((ky+4)<<3)+kx]+c64r[base+(ky<<3)+kx+4]+c64r[base+((ky+4)<<3)+kx+4];
      float ii= c64i[base+(ky<<3)+kx]+c64i[base+((ky+4)<<3)+kx]+c64i[base+(ky<<3)+kx+4]+c64i[base+((ky+4)<<3)+kx+4];
      if (lo<1){ float f=lamf[4+k2]; r+=f*pre[d*340+4+k2]; ii+=f*pim[d*340+4+k2]; }
      c16r[idx]=r; c16i[idx]=ii;
    }
  }
  __syncthreads();
  if (lo==0 && t<nd*4){
    int d=t>>2, k2=t&3, ky=k2>>1, kx=k2&1, base=d<<4;
    c4r[t]=c16r[base+(ky<<2)+kx]+c16r[base+((ky+2)<<2)+kx]+c16r[base+(ky<<2)+kx+2]+c16r[base+((ky+2)<<2)+kx+2];
    c4i[t]=c16i[base+(ky<<2)+kx]+c16i[base+((ky+2)<<2)+kx]+c16i[base+(ky<<2)+kx+2]+c16i[base+((ky+2)<<2)+kx+2];
  }
  __syncthreads();

  int dlb = d0 - g_coff[lo];
  float* vRb = ws + OFF_VRE + (size_t)(b*NM+m)*12288 + g_zo[lo];
  float* vIb = ws + OFF_VIM + (size_t)(b*NM+m)*12288 + g_zo[lo];
  const float* URg = ws + OFF_UR + (size_t)(b*NM+m)*2720;
  const float* UIg = ws + OFF_UI + (size_t)(b*NM+m)*2720;
  for (int idx=t; idx<nd*nbins; idx+=256){
    int d=idx/nbins, bin=idx-d*nbins;
    int ky=bin/ho, kx=bin-ky*ho;
    const float* pd = pre + d*340; const float* qd = pim + d*340;
    float Br = pd[((ky&1)<<1)|(kx&1)], Bi = qd[((ky&1)<<1)|(kx&1)];
    if (lo>=1){ int ix=4+(((ky&3)<<2)|(kx&3)); Br+=pd[ix]; Bi+=qd[ix]; }
    if (lo>=2){ int ix=20+(((ky&7)<<3)|(kx&7)); Br+=pd[ix]; Bi+=qd[ix]; }
    if (lo>=3){ int ix=84+(((ky&15)<<4)|(kx&15)); Br+=pd[ix]; Bi+=qd[ix]; }
    float lf = lamf[g_po[lo]+bin];
    float Vr = lf*Br, Vi = lf*Bi;
    if (lo==2){ Vr+=c64r[(d<<6)+bin]; Vi+=c64i[(d<<6)+bin]; }
    else if (lo==1){ Vr+=c16r[(d<<4)+bin]; Vi+=c16i[(d<<4)+bin]; }
    else if (lo==0){ Vr+=c4r[(d<<2)+bin]; Vi+=c4i[(d<<2)+bin]; }
    {
      int e = (g_po[lo]+bin)*8;
      const float4* ur4 = (const float4*)(URg + e);
      const float4* ui4 = (const float4*)(UIg + e);
      float4 u0=ur4[0], u1=ur4[1];
      float4 v0=ui4[0], v1=ui4[1];
      const float* sd = ssla + d*6;
      Vr += sd[0]*u0.x + sd[1]*u0.y + sd[2]*u0.z + sd[3]*u0.w + sd[4]*u1.x + sd[5]*u1.y;
      Vi += sd[0]*v0.x + sd[1]*v0.y + sd[2]*v0.z + sd[3]*v0.w + sd[4]*v1.x + sd[5]*v1.y;
    }
    int ob = (dlb+d)*nbins + bin;
    vRb[ob] = -sc*Vi;
    vIb[ob] =  sc*Vr;
  }
}

// S_zz gram + S_zw: 128-wide k-chunks (768 blocks), float4 loads
__global__ void __launch_bounds__(256) k_gram(float* __restrict__ ws){
  __shared__ float tile[32*132];
  __shared__ float wv[128];
  int t = threadIdx.x;
  int bid = blockIdx.x;
  int b = bid / 192, ch = bid % 192;
  int half = ch / 96;
  int k0 = (ch % 96) * 128;
  const float* V = ws + (half?OFF_VIM:OFF_VRE);
  const float* W = ws + (half?OFF_WIM:OFF_WRE) + b*12288 + k0;
  #pragma unroll
  for (int p=0;p<4;p++){
    int i4 = t + (p<<8);
    int row = i4 >> 5, c4 = i4 & 31;
    float4 v = *(const float4*)(V + (size_t)(b*NM+row)*12288 + k0 + (c4<<2));
    *(float4*)(tile + row*132 + (c4<<2)) = v;
  }
  if (t<128) wv[t] = W[t];
  __syncthreads();
  const float4* tf = (const float4*)tile;
  int n0 = t>>5, mm = t&31;
  float acc0=0.f, acc1=0.f, acc2=0.f, acc3=0.f;
  const float4* rm = tf + mm*33;
  const float4* r0 = tf + n0*33;
  const float4* r1 = tf + (n0+8)*33;
  const float4* r2 = tf + (n0+16)*33;
  const float4* r3 = tf + (n0+24)*33;
  for (int k4=0;k4<32;k4++){
    float4 vm = rm[k4];
    float4 v0 = r0[k4];
    float4 v1 = r1[k4];
    float4 v2 = r2[k4];
    float4 v3 = r3[k4];
    acc0 += v0.x*vm.x + v0.y*vm.y + v0.z*vm.z + v0.w*vm.w;
    acc1 += v1.x*vm.x + v1.y*vm.y + v1.z*vm.z + v1.w*vm.w;
    acc2 += v2.x*vm.x + v2.y*vm.y + v2.z*vm.z + v2.w*vm.w;
    acc3 += v3.x*vm.x + v3.y*vm.y + v3.z*vm.z + v3.w*vm.w;
  }
  float* szz = ws + OFF_SZZ + (b<<10);
  atomicAdd(&szz[(n0<<5) + mm], acc0);
  atomicAdd(&szz[((n0+8)<<5) + mm], acc1);
  atomicAdd(&szz[((n0+16)<<5) + mm], acc2);
  atomicAdd(&szz[((n0+24)<<5) + mm], acc3);
  if (t < 32){
    const float4* rn = tf + t*33;
    const float4* wf = (const float4*)wv;
    float acc=0.f;
    for (int k4=0;k4<32;k4++){
      float4 a = rn[k4]; float4 wq = wf[k4];
      acc += a.x*wq.x + a.y*wq.y + a.z*wq.z + a.w*wq.w;
    }
    atomicAdd(&ws[OFF_SZW + (b<<5) + t], acc);
  }
}

// var, normalize, Cholesky 32x32 in LDS, logdet, trace, output
__global__ void k_final(float* __restrict__ ws, float* __restrict__ out){
  __shared__ float A[32][33];
  __shared__ float svar;
  int b = blockIdx.x, t = threadIdx.x;
  const float* szz = ws + OFF_SZZ + (b<<10);
  if (t==0){
    float s=0.f;
    for (int i=0;i<32;i++) s += szz[i*33];
    svar = fmaxf(s/32.0f, 1e-6f);
  }
  __syncthreads();
  float var = svar;
  for (int i=t;i<1024;i+=64){
    int r=i>>5, c=i&31;
    A[r][c] = szz[i]/var + ((r==c)?EPSV:0.0f);
  }
  __syncthreads();
  for (int j=0;j<32;j++){
    if (t==0) A[j][j] = sqrtf(A[j][j]);
    __syncthreads();
    if (t>j && t<32) A[t][j] /= A[j][j];
    __syncthreads();
    if (t>j && t<32){
      float lij = A[t][j];
      for (int k=j+1;k<=t;k++) A[t][k] -= lij*A[k][j];
    }
    __syncthreads();
  }
  if (t==0){
    float logdet=0.f;
    for (int j=0;j<32;j++) logdet += logf(A[j][j]);
    logdet *= 2.0f;
    const float* szw = ws + OFF_SZW + (b<<5);
    float s2=0.f;
    for (int n=0;n<32;n++) s2 += szw[n]*szw[n];
    float trace = EPSV*ws[OFF_SWW + b] + s2/var;
    out[b] = 0.5f*(logdet - trace);
  }
}

extern "C" void kernel_launch(void* const* d_in, const int* in_sizes, int n_in,
                              void* d_out, int out_size, void* d_ws, size_t ws_size,
                              hipStream_t stream){
  // setup_inputs() dict order is INTERLEAVED: z0,w0,z1,w1,z2,w2,z3,w3,z4,w4,L,lam
  const float* z0 = (const float*)d_in[0];
  const float* w0 = (const float*)d_in[1];
  const float* z1 = (const float*)d_in[2];
  const float* w1 = (const float*)d_in[3];
  const float* z2 = (const float*)d_in[4];
  const float* w2 = (const float*)d_in[5];
  const float* z3 = (const float*)d_in[6];
  const float* w3 = (const float*)d_in[7];
  const float* z4 = (const float*)d_in[8];
  const float* w4 = (const float*)d_in[9];
  const float* L   = (const float*)d_in[10];
  const float* lam = (const float*)d_in[11];
  float* ws = (float*)d_ws;
  float* out = (float*)d_out;

  k_pre<<<PRE_UGEN, 256, 0, stream>>>(z0,z1,z2,z3,z4,w0,w1,w2,w3,w4, L, lam, ws);
  k_fold<<<NB*NM*48, 256, 0, stream>>>(ws);
  k_gram<<<NB*192, 256, 0, stream>>>(ws);
  k_final<<<NB, 64, 0, stream>>>(ws, out);
}